// Round 1
// baseline (370.293 us; speedup 1.0000x reference)
//
#include <hip/hip_runtime.h>
#include <hip/hip_bf16.h>

// out[n] = sum_k U[k] * relu( x1[n,:] . M[k,:] + c[k] )
//   M[k,d] = V[k,d] + sum_e W[k,d,e]*x2[e]
//   c[k]   = sum_e V[k,128+e]*x2[e] + b[k]

#define D 128
#define KK 16
#define TPB 256
#define CHUNK 32      // d-columns per chunk
#define NCHUNK (D / CHUNK)

// ---------- prep: build M (K x D) and c (K) in workspace ----------
__global__ void ntn_prep(const float* __restrict__ x2,
                         const float* __restrict__ V,
                         const float* __restrict__ W,
                         const float* __restrict__ b,
                         float* __restrict__ M,
                         float* __restrict__ c) {
    int k = blockIdx.x;      // 0..15
    int d = threadIdx.x;     // 0..127
    __shared__ float x2s[D];
    __shared__ float red[D];
    x2s[d] = x2[d];
    __syncthreads();

    const float* Wrow = W + ((size_t)k * D + d) * D;
    float s = 0.f;
#pragma unroll 8
    for (int e = 0; e < D; ++e) s = fmaf(Wrow[e], x2s[e], s);
    M[k * D + d] = V[k * 2 * D + d] + s;

    red[d] = V[k * 2 * D + D + d] * x2s[d];
    __syncthreads();
    for (int off = D / 2; off > 0; off >>= 1) {
        if (d < off) red[d] += red[d + off];
        __syncthreads();
    }
    if (d == 0) c[k] = red[0] + b[k];
}

// ---------- main: one row per thread, 256-row tile, 4 d-chunks ----------
__global__ __launch_bounds__(TPB) void ntn_main(const float* __restrict__ x1,
                                                const float* __restrict__ M,
                                                const float* __restrict__ c,
                                                const float* __restrict__ U,
                                                float* __restrict__ out,
                                                int N) {
    __shared__ float xt[TPB][CHUNK + 1];   // +1 pad: compute reads hit bank (t+j)%32 -> 2-way (free)

    const int t = threadIdx.x;
    const int row0 = blockIdx.x * TPB;

    float acc[KK];
#pragma unroll
    for (int k = 0; k < KK; ++k) acc[k] = 0.f;

    const float4* __restrict__ src = (const float4*)x1;  // row stride = 32 float4

    for (int ch = 0; ch < NCHUNK; ++ch) {
        // ---- stage: 256 rows x 32 cols, coalesced float4 ----
#pragma unroll
        for (int i = 0; i < 8; ++i) {
            int f = i * TPB + t;          // 0..2047
            int r = f >> 3;               // tile row
            int jj = f & 7;               // float4 within chunk
            int grow = row0 + r;
            float4 v = make_float4(0.f, 0.f, 0.f, 0.f);
            if (grow < N) v = src[grow * 32 + ch * 8 + jj];
            xt[r][jj * 4 + 0] = v.x;
            xt[r][jj * 4 + 1] = v.y;
            xt[r][jj * 4 + 2] = v.z;
            xt[r][jj * 4 + 3] = v.w;
        }
        __syncthreads();

        // ---- pull my row chunk into registers ----
        float xr[CHUNK];
#pragma unroll
        for (int j = 0; j < CHUNK; ++j) xr[j] = xt[t][j];

        // ---- 16 x 32 FMA; M indices are wave-uniform -> s_load + v_fmac ----
        const float* __restrict__ Mc = M + ch * CHUNK;
#pragma unroll
        for (int k = 0; k < KK; ++k) {
            float a = acc[k];
            const float* __restrict__ Mk = Mc + k * D;
#pragma unroll
            for (int j = 0; j < CHUNK; ++j) a = fmaf(xr[j], Mk[j], a);
            acc[k] = a;
        }
        __syncthreads();
    }

    const int row = row0 + t;
    if (row < N) {
        float s = 0.f;
#pragma unroll
        for (int k = 0; k < KK; ++k)
            s = fmaf(U[k], fmaxf(acc[k] + c[k], 0.f), s);
        out[row] = s;
    }
}

extern "C" void kernel_launch(void* const* d_in, const int* in_sizes, int n_in,
                              void* d_out, int out_size, void* d_ws, size_t ws_size,
                              hipStream_t stream) {
    const float* x1 = (const float*)d_in[0];
    const float* x2 = (const float*)d_in[1];
    const float* V  = (const float*)d_in[2];
    const float* W  = (const float*)d_in[3];
    const float* b  = (const float*)d_in[4];
    const float* U  = (const float*)d_in[5];
    float* out = (float*)d_out;

    float* M = (float*)d_ws;          // K*D floats
    float* c = M + KK * D;            // K floats

    const int N = in_sizes[0] / D;    // 500000

    ntn_prep<<<KK, D, 0, stream>>>(x2, V, W, b, M, c);

    int grid = (N + TPB - 1) / TPB;
    ntn_main<<<grid, TPB, 0, stream>>>(x1, M, c, U, out, N);
}